// Round 1
// baseline (332.142 us; speedup 1.0000x reference)
//
#include <hip/hip_runtime.h>
#include <stdint.h>

#define D_IN   4096
#define D_OUT  4096
#define NTOK   4096
#define NW     (D_OUT * D_IN)          // 16777216
#define RANK1  15099493u               // floor(0.9f * (NW-1)) as jax computes in f32

typedef unsigned int  uint32;
typedef unsigned short ushort_t;
typedef float  f32x4  __attribute__((ext_vector_type(4)));
typedef __bf16 bf16x8 __attribute__((ext_vector_type(8)));

// ---------- helpers ----------
__device__ __forceinline__ uint32 rne_bf16(float f) {
  uint32 u = __float_as_uint(f);
  return (u + 0x7FFFu + ((u >> 16) & 1u)) >> 16;
}

__device__ __forceinline__ void gload_lds16(const void* g, void* l) {
  __builtin_amdgcn_global_load_lds((__attribute__((address_space(1))) void*)(g),
                                   (__attribute__((address_space(3))) void*)(l), 16, 0, 0);
}

// ---------- threshold selection (exact radix select on |w| bits) ----------
__global__ void hist_pass1(const uint4* __restrict__ wb, uint32* __restrict__ hist) {
  __shared__ uint32 lh[2048];
  for (int i = threadIdx.x; i < 2048; i += 256) lh[i] = 0;
  __syncthreads();
  int idx = blockIdx.x * 256 + threadIdx.x;
  int stride = gridDim.x * 256;
  for (int i = idx; i < NW / 4; i += stride) {
    uint4 v = wb[i];
    atomicAdd(&lh[(v.x & 0x7FFFFFFFu) >> 20], 1u);
    atomicAdd(&lh[(v.y & 0x7FFFFFFFu) >> 20], 1u);
    atomicAdd(&lh[(v.z & 0x7FFFFFFFu) >> 20], 1u);
    atomicAdd(&lh[(v.w & 0x7FFFFFFFu) >> 20], 1u);
  }
  __syncthreads();
  for (int i = threadIdx.x; i < 2048; i += 256) { uint32 c = lh[i]; if (c) atomicAdd(&hist[i], c); }
}

__global__ void hist_pass23(const uint4* __restrict__ wb, const uint32* __restrict__ state,
                            uint32* __restrict__ hist, int pass) {
  __shared__ uint32 lh[1024];
  for (int i = threadIdx.x; i < 1024; i += 256) lh[i] = 0;
  __syncthreads();
  uint32 pref = state[pass == 2 ? 0 : 2];
  int fsh = (pass == 2) ? 20 : 10;   // filter shift
  int bsh = (pass == 2) ? 10 : 0;    // bin shift
  int idx = blockIdx.x * 256 + threadIdx.x;
  int stride = gridDim.x * 256;
  for (int i = idx; i < NW / 4; i += stride) {
    uint4 v = wb[i];
    uint32 k;
    k = v.x & 0x7FFFFFFFu; if ((k >> fsh) == pref) atomicAdd(&lh[(k >> bsh) & 1023u], 1u);
    k = v.y & 0x7FFFFFFFu; if ((k >> fsh) == pref) atomicAdd(&lh[(k >> bsh) & 1023u], 1u);
    k = v.z & 0x7FFFFFFFu; if ((k >> fsh) == pref) atomicAdd(&lh[(k >> bsh) & 1023u], 1u);
    k = v.w & 0x7FFFFFFFu; if ((k >> fsh) == pref) atomicAdd(&lh[(k >> bsh) & 1023u], 1u);
  }
  __syncthreads();
  for (int i = threadIdx.x; i < 1024; i += 256) { uint32 c = lh[i]; if (c) atomicAdd(&hist[i], c); }
}

// one block of 256 threads: block-wide scan, find bin containing target rank
__global__ void scan_select(const uint32* __restrict__ hist, int nbins,
                            uint32* __restrict__ state, int pass) {
  int tid = threadIdx.x;
  int per = nbins >> 8;           // 8 (pass1) or 4 (pass2/3)
  uint32 loc[8];
  uint32 s = 0;
  int base = tid * per;
  for (int i = 0; i < per; i++) { loc[i] = hist[base + i]; s += loc[i]; }
  int lane = tid & 63, wid = tid >> 6;
  uint32 v = s;
  for (int d = 1; d < 64; d <<= 1) { uint32 o = __shfl_up(v, (unsigned)d); if (lane >= d) v += o; }
  __shared__ uint32 wtot[4];
  if (lane == 63) wtot[wid] = v;
  __syncthreads();
  uint32 woff = 0;
  for (int w = 0; w < wid; w++) woff += wtot[w];
  uint32 incl = v + woff;
  uint32 excl = incl - s;
  uint32 rank = (pass == 1) ? RANK1 : state[(pass == 2) ? 1 : 3];
  if (rank >= excl && rank < incl) {
    uint32 c = excl; int b = base;
    for (int i = 0; i < per; i++) {
      if (rank < c + loc[i]) { b = base + i; break; }
      c += loc[i];
    }
    uint32 rw = rank - c;
    if (pass == 1)      { state[0] = (uint32)b; state[1] = rw; }
    else if (pass == 2) { state[2] = (state[0] << 10) | (uint32)b; state[3] = rw; }
    else                { state[4] = (state[2] << 10) | (uint32)b; }   // v1 bit pattern
  }
}

// ---------- conversions ----------
__global__ void convert_w(const float4* __restrict__ w, const uint32* __restrict__ state,
                          uint4* __restrict__ out) {
  float thr = __uint_as_float(state[4]);
  int i = blockIdx.x * 256 + threadIdx.x;
  int stride = gridDim.x * 256;
  for (; i < NW / 8; i += stride) {
    float4 a = w[2 * i], b = w[2 * i + 1];
    float f[8] = {a.x, a.y, a.z, a.w, b.x, b.y, b.z, b.w};
    uint32 h[8];
#pragma unroll
    for (int j = 0; j < 8; j++) h[j] = (fabsf(f[j]) > thr) ? rne_bf16(f[j]) : 0u;
    uint4 o;
    o.x = h[0] | (h[1] << 16);
    o.y = h[2] | (h[3] << 16);
    o.z = h[4] | (h[5] << 16);
    o.w = h[6] | (h[7] << 16);
    out[i] = o;
  }
}

__global__ void convert_x(const float4* __restrict__ x, uint4* __restrict__ out) {
  int i = blockIdx.x * 256 + threadIdx.x;
  int stride = gridDim.x * 256;
  for (; i < NW / 8; i += stride) {
    float4 a = x[2 * i], b = x[2 * i + 1];
    uint4 o;
    o.x = rne_bf16(a.x) | (rne_bf16(a.y) << 16);
    o.y = rne_bf16(a.z) | (rne_bf16(a.w) << 16);
    o.z = rne_bf16(b.x) | (rne_bf16(b.y) << 16);
    o.w = rne_bf16(b.z) | (rne_bf16(b.w) << 16);
    out[i] = o;
  }
}

// ---------- GEMM: C[M,N] = Xb[M,K] * Wb[N,K]^T + bias, bf16 in / f32 out ----------
#define BM 128
#define BN 128
#define BK 32

__global__ __launch_bounds__(256) void gemm_bt(const ushort_t* __restrict__ A,
                                               const ushort_t* __restrict__ B,
                                               const float* __restrict__ bias,
                                               float* __restrict__ C) {
  __shared__ __align__(16) ushort_t lA[BM * BK];   // 8 KB
  __shared__ __align__(16) ushort_t lB[BN * BK];   // 8 KB

  int nwg = gridDim.x;                  // 1024, divisible by 8
  int bid = blockIdx.x;
  int cpx = nwg >> 3;
  int swz = (bid & 7) * cpx + (bid >> 3);   // bijective XCD swizzle
  int bm = swz >> 5;                        // 32 row-blocks
  int bn = swz & 31;                        // 32 col-blocks

  int tid  = threadIdx.x;
  int lane = tid & 63;

  int wave = tid >> 6;
  int wr = wave >> 1, wc = wave & 1;        // 2x2 wave grid, 64x64 per wave

  const ushort_t* Abase = A + (size_t)(bm * BM) * D_IN;
  const ushort_t* Bbase = B + (size_t)(bn * BN) * D_IN;

  // staging: chunk c covers lds elements [c*8, c*8+8); row = c>>2, k-quad = c&3
  int c0 = tid, c1 = 256 + tid;
  int r0 = c0 >> 2, q0 = c0 & 3;
  int r1 = c1 >> 2, q1 = c1 & 3;

  // fragment read addresses (constant across K loop)
  int arow = wr * 64 + (lane & 15);
  int brow = wc * 64 + (lane & 15);
  int kq   = lane >> 4;                     // which 8-chunk of K
  const bf16x8* lA8 = (const bf16x8*)lA;
  const bf16x8* lB8 = (const bf16x8*)lB;

  f32x4 acc[4][4];
#pragma unroll
  for (int m = 0; m < 4; m++)
#pragma unroll
    for (int n = 0; n < 4; n++) acc[m][n] = (f32x4){0.f, 0.f, 0.f, 0.f};

  for (int kt = 0; kt < D_IN; kt += BK) {
    __syncthreads();
    gload_lds16(Abase + (size_t)r0 * D_IN + kt + q0 * 8, &lA[c0 * 8]);
    gload_lds16(Abase + (size_t)r1 * D_IN + kt + q1 * 8, &lA[c1 * 8]);
    gload_lds16(Bbase + (size_t)r0 * D_IN + kt + q0 * 8, &lB[c0 * 8]);
    gload_lds16(Bbase + (size_t)r1 * D_IN + kt + q1 * 8, &lB[c1 * 8]);
    __syncthreads();

    bf16x8 af[4], bfr[4];
#pragma unroll
    for (int m = 0; m < 4; m++) af[m] = lA8[(arow + m * 16) * 4 + kq];
#pragma unroll
    for (int n = 0; n < 4; n++) bfr[n] = lB8[(brow + n * 16) * 4 + kq];
#pragma unroll
    for (int m = 0; m < 4; m++)
#pragma unroll
      for (int n = 0; n < 4; n++)
        acc[m][n] = __builtin_amdgcn_mfma_f32_16x16x32_bf16(af[m], bfr[n], acc[m][n], 0, 0, 0);
  }

  int orow0 = bm * BM + wr * 64 + (lane >> 4) * 4;
  int ocol0 = bn * BN + wc * 64 + (lane & 15);
#pragma unroll
  for (int n = 0; n < 4; n++) {
    float bv = bias[ocol0 + n * 16];
#pragma unroll
    for (int m = 0; m < 4; m++) {
#pragma unroll
      for (int r = 0; r < 4; r++) {
        C[(size_t)(orow0 + m * 16 + r) * D_OUT + ocol0 + n * 16] = acc[m][n][r] + bv;
      }
    }
  }
}

// ---------- launch ----------
extern "C" void kernel_launch(void* const* d_in, const int* in_sizes, int n_in,
                              void* d_out, int out_size, void* d_ws, size_t ws_size,
                              hipStream_t stream) {
  const float* x = (const float*)d_in[0];
  const float* w = (const float*)d_in[1];
  const float* bias = (const float*)d_in[2];
  float* out = (float*)d_out;

  char* ws = (char*)d_ws;
  uint32* hist1 = (uint32*)ws;                 // 2048 bins
  uint32* hist2 = (uint32*)(ws + 8192);        // 1024 bins
  uint32* hist3 = (uint32*)(ws + 12288);       // 1024 bins
  uint32* state = (uint32*)(ws + 16384);       // 16 slots
  ushort_t* Xb = (ushort_t*)(ws + 65536);
  ushort_t* Wb = (ushort_t*)(ws + 65536 + (size_t)NW * 2);

  hipMemsetAsync(d_ws, 0, 16448, stream);

  hist_pass1<<<2048, 256, 0, stream>>>((const uint4*)w, hist1);
  scan_select<<<1, 256, 0, stream>>>(hist1, 2048, state, 1);
  hist_pass23<<<2048, 256, 0, stream>>>((const uint4*)w, state, hist2, 2);
  scan_select<<<1, 256, 0, stream>>>(hist2, 1024, state, 2);
  hist_pass23<<<2048, 256, 0, stream>>>((const uint4*)w, state, hist3, 3);
  scan_select<<<1, 256, 0, stream>>>(hist3, 1024, state, 3);

  convert_w<<<2048, 256, 0, stream>>>((const float4*)w, state, (uint4*)Wb);
  convert_x<<<2048, 256, 0, stream>>>((const float4*)x, (uint4*)Xb);

  gemm_bt<<<1024, 256, 0, stream>>>(Xb, Wb, bias, out);
}

// Round 2
// 275.981 us; speedup vs baseline: 1.2035x; 1.2035x over previous
//
#include <hip/hip_runtime.h>
#include <stdint.h>

#define D_IN   4096
#define D_OUT  4096
#define NTOK   4096
#define NW     (D_OUT * D_IN)          // 16777216
#define RANK1  15099493u               // floor(0.9f * (NW-1)) as jax computes in f32

typedef unsigned int  uint32;
typedef unsigned short ushort_t;
typedef float  f32x4  __attribute__((ext_vector_type(4)));
typedef __bf16 bf16x8 __attribute__((ext_vector_type(8)));

// ---------- helpers ----------
__device__ __forceinline__ uint32 rne_bf16(float f) {
  uint32 u = __float_as_uint(f);
  return (u + 0x7FFFu + ((u >> 16) & 1u)) >> 16;
}

__device__ __forceinline__ void gload_lds16(const void* g, void* l) {
  __builtin_amdgcn_global_load_lds((__attribute__((address_space(1))) void*)(g),
                                   (__attribute__((address_space(3))) void*)(l), 16, 0, 0);
}

// ---------- threshold selection (exact radix select on |w| bits) ----------
__global__ void hist_pass1(const uint4* __restrict__ wb, uint32* __restrict__ hist) {
  __shared__ uint32 lh[2048];
  for (int i = threadIdx.x; i < 2048; i += 256) lh[i] = 0;
  __syncthreads();
  int idx = blockIdx.x * 256 + threadIdx.x;
  int stride = gridDim.x * 256;
  for (int i = idx; i < NW / 4; i += stride) {
    uint4 v = wb[i];
    atomicAdd(&lh[(v.x & 0x7FFFFFFFu) >> 20], 1u);
    atomicAdd(&lh[(v.y & 0x7FFFFFFFu) >> 20], 1u);
    atomicAdd(&lh[(v.z & 0x7FFFFFFFu) >> 20], 1u);
    atomicAdd(&lh[(v.w & 0x7FFFFFFFu) >> 20], 1u);
  }
  __syncthreads();
  for (int i = threadIdx.x; i < 2048; i += 256) { uint32 c = lh[i]; if (c) atomicAdd(&hist[i], c); }
}

__global__ void hist_pass23(const uint4* __restrict__ wb, const uint32* __restrict__ state,
                            uint32* __restrict__ hist, int pass) {
  __shared__ uint32 lh[1024];
  for (int i = threadIdx.x; i < 1024; i += 256) lh[i] = 0;
  __syncthreads();
  uint32 pref = state[pass == 2 ? 0 : 2];
  int fsh = (pass == 2) ? 20 : 10;   // filter shift
  int bsh = (pass == 2) ? 10 : 0;    // bin shift
  int idx = blockIdx.x * 256 + threadIdx.x;
  int stride = gridDim.x * 256;
  for (int i = idx; i < NW / 4; i += stride) {
    uint4 v = wb[i];
    uint32 k;
    k = v.x & 0x7FFFFFFFu; if ((k >> fsh) == pref) atomicAdd(&lh[(k >> bsh) & 1023u], 1u);
    k = v.y & 0x7FFFFFFFu; if ((k >> fsh) == pref) atomicAdd(&lh[(k >> bsh) & 1023u], 1u);
    k = v.z & 0x7FFFFFFFu; if ((k >> fsh) == pref) atomicAdd(&lh[(k >> bsh) & 1023u], 1u);
    k = v.w & 0x7FFFFFFFu; if ((k >> fsh) == pref) atomicAdd(&lh[(k >> bsh) & 1023u], 1u);
  }
  __syncthreads();
  for (int i = threadIdx.x; i < 1024; i += 256) { uint32 c = lh[i]; if (c) atomicAdd(&hist[i], c); }
}

// one block of 256 threads: block-wide scan, find bin containing target rank
__global__ void scan_select(const uint32* __restrict__ hist, int nbins,
                            uint32* __restrict__ state, int pass) {
  int tid = threadIdx.x;
  int per = nbins >> 8;           // 8 (pass1) or 4 (pass2/3)
  uint32 loc[8];
  uint32 s = 0;
  int base = tid * per;
  for (int i = 0; i < per; i++) { loc[i] = hist[base + i]; s += loc[i]; }
  int lane = tid & 63, wid = tid >> 6;
  uint32 v = s;
  for (int d = 1; d < 64; d <<= 1) { uint32 o = __shfl_up(v, (unsigned)d); if (lane >= d) v += o; }
  __shared__ uint32 wtot[4];
  if (lane == 63) wtot[wid] = v;
  __syncthreads();
  uint32 woff = 0;
  for (int w = 0; w < wid; w++) woff += wtot[w];
  uint32 incl = v + woff;
  uint32 excl = incl - s;
  uint32 rank = (pass == 1) ? RANK1 : state[(pass == 2) ? 1 : 3];
  if (rank >= excl && rank < incl) {
    uint32 c = excl; int b = base;
    for (int i = 0; i < per; i++) {
      if (rank < c + loc[i]) { b = base + i; break; }
      c += loc[i];
    }
    uint32 rw = rank - c;
    if (pass == 1)      { state[0] = (uint32)b; state[1] = rw; }
    else if (pass == 2) { state[2] = (state[0] << 10) | (uint32)b; state[3] = rw; }
    else                { state[4] = (state[2] << 10) | (uint32)b; }   // v1 bit pattern
  }
}

// ---------- conversions ----------
__global__ void convert_w(const float4* __restrict__ w, const uint32* __restrict__ state,
                          uint4* __restrict__ out) {
  float thr = __uint_as_float(state[4]);
  int i = blockIdx.x * 256 + threadIdx.x;
  int stride = gridDim.x * 256;
  for (; i < NW / 8; i += stride) {
    float4 a = w[2 * i], b = w[2 * i + 1];
    float f[8] = {a.x, a.y, a.z, a.w, b.x, b.y, b.z, b.w};
    uint32 h[8];
#pragma unroll
    for (int j = 0; j < 8; j++) h[j] = (fabsf(f[j]) > thr) ? rne_bf16(f[j]) : 0u;
    uint4 o;
    o.x = h[0] | (h[1] << 16);
    o.y = h[2] | (h[3] << 16);
    o.z = h[4] | (h[5] << 16);
    o.w = h[6] | (h[7] << 16);
    out[i] = o;
  }
}

__global__ void convert_x(const float4* __restrict__ x, uint4* __restrict__ out) {
  int i = blockIdx.x * 256 + threadIdx.x;
  int stride = gridDim.x * 256;
  for (; i < NW / 8; i += stride) {
    float4 a = x[2 * i], b = x[2 * i + 1];
    uint4 o;
    o.x = rne_bf16(a.x) | (rne_bf16(a.y) << 16);
    o.y = rne_bf16(a.z) | (rne_bf16(a.w) << 16);
    o.z = rne_bf16(b.x) | (rne_bf16(b.y) << 16);
    o.w = rne_bf16(b.z) | (rne_bf16(b.w) << 16);
    out[i] = o;
  }
}

// ---------- GEMM: C[M,N] = Xb[M,K] * Wb[N,K]^T + bias, bf16 in / f32 out ----------
// 256x256 tile, BK=32, 8 waves (2x4), triple-buffered LDS, 2 phases/K-tile,
// counted vmcnt(4) at tile boundaries only, LDS k-chunk XOR swizzle (T2),
// setprio around MFMA cluster (T5), XCD-swizzled grid (T1).
#define TILES 128   // 4096 / 32

// stage one 256x32 bf16 panel (16KB) into LDS: 2 x global_load_lds(16B)/thread.
// LDS dest linear; swizzle applied to GLOBAL source k-chunk (rule 21).
__device__ __forceinline__ void stage16k(const ushort_t* __restrict__ G, int rowbase, int kt,
                                         ushort_t* lbase, int tid) {
#pragma unroll
  for (int j = 0; j < 2; j++) {
    int idx = j * 512 + tid;              // 16B-chunk index 0..1023
    int r = idx >> 2;                     // row 0..255
    int cl = (idx & 3) ^ ((r >> 1) & 3);  // logical k-chunk for this physical slot
    gload_lds16(G + (size_t)(rowbase + r) * D_IN + kt + cl * 8, lbase + idx * 8);
  }
}

__global__ __launch_bounds__(512, 2) void gemm_bt(const ushort_t* __restrict__ A,
                                                  const ushort_t* __restrict__ B,
                                                  const float* __restrict__ bias,
                                                  float* __restrict__ C) {
  extern __shared__ ushort_t lds[];   // 3 bufs x (A 8192 + B 8192) elems = 96KB

  int bid = blockIdx.x;                     // 256 blocks
  int swz = (bid & 7) * 32 + (bid >> 3);    // bijective XCD swizzle (256 % 8 == 0)
  int bm = swz >> 4;                        // 16 row-blocks
  int bn = swz & 15;                        // 16 col-blocks

  int tid  = threadIdx.x;
  int lane = tid & 63;
  int wave = tid >> 6;
  int wm = wave >> 2, wn = wave & 3;        // 2x4 wave grid: 128x64 per wave

  int l15  = lane & 15;
  int csel = (lane >> 4) ^ ((lane >> 1) & 3);  // swizzled k-chunk for frag reads

  const ushort_t* Ag = A;
  const ushort_t* Bg = B;

  f32x4 acc[8][4];
#pragma unroll
  for (int m = 0; m < 8; m++)
#pragma unroll
    for (int n = 0; n < 4; n++) acc[m][n] = (f32x4){0.f, 0.f, 0.f, 0.f};

  // prologue: stage tiles 0 and 1
  stage16k(Ag, bm * 256, 0,  lds,                 tid);
  stage16k(Bg, bn * 256, 0,  lds + 8192,          tid);
  stage16k(Ag, bm * 256, 32, lds + 16384,         tid);
  stage16k(Bg, bn * 256, 32, lds + 16384 + 8192,  tid);
  asm volatile("s_waitcnt vmcnt(4)" ::: "memory");   // tile 0 landed; tile 1 in flight
  asm volatile("s_barrier" ::: "memory");

  int cur = 0, sd = 2;
  for (int t = 0; t < TILES; t++) {
    int u = t + 2; if (u > TILES - 1) u = TILES - 1;   // clamped prefetch keeps vmcnt uniform
    int kup = u * 32;
    ushort_t* sbase = lds + sd * 16384;
    const bf16x8* A8 = (const bf16x8*)(lds + cur * 16384);
    const bf16x8* B8 = A8 + 1024;

#pragma unroll
    for (int qm = 0; qm < 2; qm++) {
      // ds-read this phase's fragments (issued before barrier; consumed after lgkmcnt(0))
      bf16x8 af[4], bv[4];
      int ar = wm * 128 + qm * 64 + l15;
      int br = wn * 64 + l15;
#pragma unroll
      for (int mm = 0; mm < 4; mm++) af[mm] = A8[(ar + mm * 16) * 4 + csel];
#pragma unroll
      for (int n = 0; n < 4; n++)    bv[n] = B8[(br + n * 16) * 4 + csel];

      // stage one panel of tile t+2 into the buffer not being read
      if (qm == 0) stage16k(Ag, bm * 256, kup, sbase, tid);
      else         stage16k(Bg, bn * 256, kup, sbase + 8192, tid);

      asm volatile("s_barrier" ::: "memory");
      asm volatile("s_waitcnt lgkmcnt(0)" ::: "memory");
      __builtin_amdgcn_sched_barrier(0);
      __builtin_amdgcn_s_setprio(1);
#pragma unroll
      for (int mm = 0; mm < 4; mm++)
#pragma unroll
        for (int n = 0; n < 4; n++)
          acc[qm * 4 + mm][n] =
              __builtin_amdgcn_mfma_f32_16x16x32_bf16(af[mm], bv[n], acc[qm * 4 + mm][n], 0, 0, 0);
      __builtin_amdgcn_s_setprio(0);
      __builtin_amdgcn_sched_barrier(0);
      if (qm == 1) asm volatile("s_waitcnt vmcnt(4)" ::: "memory");  // counted, never 0
      asm volatile("s_barrier" ::: "memory");
    }
    cur = (cur == 2) ? 0 : cur + 1;
    sd  = (sd  == 2) ? 0 : sd + 1;
  }

  int orow0 = bm * 256 + wm * 128 + (lane >> 4) * 4;
  int ocol0 = bn * 256 + wn * 64 + l15;
#pragma unroll
  for (int n = 0; n < 4; n++) {
    float bv2 = bias[ocol0 + n * 16];
#pragma unroll
    for (int m = 0; m < 8; m++) {
#pragma unroll
      for (int r = 0; r < 4; r++) {
        C[(size_t)(orow0 + m * 16 + r) * D_OUT + ocol0 + n * 16] = acc[m][n][r] + bv2;
      }
    }
  }
}

// ---------- launch ----------
extern "C" void kernel_launch(void* const* d_in, const int* in_sizes, int n_in,
                              void* d_out, int out_size, void* d_ws, size_t ws_size,
                              hipStream_t stream) {
  const float* x = (const float*)d_in[0];
  const float* w = (const float*)d_in[1];
  const float* bias = (const float*)d_in[2];
  float* out = (float*)d_out;

  char* ws = (char*)d_ws;
  uint32* hist1 = (uint32*)ws;                 // 2048 bins
  uint32* hist2 = (uint32*)(ws + 8192);        // 1024 bins
  uint32* hist3 = (uint32*)(ws + 12288);       // 1024 bins
  uint32* state = (uint32*)(ws + 16384);       // 16 slots
  ushort_t* Xb = (ushort_t*)(ws + 65536);
  ushort_t* Wb = (ushort_t*)(ws + 65536 + (size_t)NW * 2);

  hipMemsetAsync(d_ws, 0, 16448, stream);

  hist_pass1<<<2048, 256, 0, stream>>>((const uint4*)w, hist1);
  scan_select<<<1, 256, 0, stream>>>(hist1, 2048, state, 1);
  hist_pass23<<<2048, 256, 0, stream>>>((const uint4*)w, state, hist2, 2);
  scan_select<<<1, 256, 0, stream>>>(hist2, 1024, state, 2);
  hist_pass23<<<2048, 256, 0, stream>>>((const uint4*)w, state, hist3, 3);
  scan_select<<<1, 256, 0, stream>>>(hist3, 1024, state, 3);

  convert_w<<<2048, 256, 0, stream>>>((const float4*)w, state, (uint4*)Wb);
  convert_x<<<2048, 256, 0, stream>>>((const float4*)x, (uint4*)Xb);

  gemm_bt<<<256, 512, 98304, stream>>>(Xb, Wb, bias, out);
}

// Round 3
// 257.909 us; speedup vs baseline: 1.2878x; 1.0701x over previous
//
#include <hip/hip_runtime.h>
#include <stdint.h>

#define D_IN   4096
#define D_OUT  4096
#define NTOK   4096
#define NW     (D_OUT * D_IN)          // 16777216
#define RANK1  15099493u               // floor(0.9f * (NW-1)) as jax computes in f32

typedef unsigned int  uint32;
typedef unsigned short ushort_t;
typedef float  f32x4  __attribute__((ext_vector_type(4)));
typedef __bf16 bf16x8 __attribute__((ext_vector_type(8)));

// ---------- helpers ----------
__device__ __forceinline__ uint32 rne_bf16(float f) {
  uint32 u = __float_as_uint(f);
  return (u + 0x7FFFu + ((u >> 16) & 1u)) >> 16;
}

__device__ __forceinline__ void gload_lds16(const void* g, void* l) {
  __builtin_amdgcn_global_load_lds((__attribute__((address_space(1))) void*)(g),
                                   (__attribute__((address_space(3))) void*)(l), 16, 0, 0);
}

// ---------- threshold selection (exact radix select on |w| bits) ----------
// per-wave private histograms: normal weights hit ~64 hot bins -> atomics serialize;
// 4-way privatization cuts conflict depth 4x.
__global__ void hist_pass1(const uint4* __restrict__ wb, uint32* __restrict__ hist) {
  __shared__ uint32 lh[4][2048];
  for (int i = threadIdx.x; i < 8192; i += 256) ((uint32*)lh)[i] = 0;
  __syncthreads();
  int wid = threadIdx.x >> 6;
  int idx = blockIdx.x * 256 + threadIdx.x;
  int stride = gridDim.x * 256;
  for (int i = idx; i < NW / 4; i += stride) {
    uint4 v = wb[i];
    atomicAdd(&lh[wid][(v.x & 0x7FFFFFFFu) >> 20], 1u);
    atomicAdd(&lh[wid][(v.y & 0x7FFFFFFFu) >> 20], 1u);
    atomicAdd(&lh[wid][(v.z & 0x7FFFFFFFu) >> 20], 1u);
    atomicAdd(&lh[wid][(v.w & 0x7FFFFFFFu) >> 20], 1u);
  }
  __syncthreads();
  for (int i = threadIdx.x; i < 2048; i += 256) {
    uint32 c = lh[0][i] + lh[1][i] + lh[2][i] + lh[3][i];
    if (c) atomicAdd(&hist[i], c);
  }
}

__global__ void hist_pass23(const uint4* __restrict__ wb, const uint32* __restrict__ state,
                            uint32* __restrict__ hist, int pass) {
  __shared__ uint32 lh[1024];
  for (int i = threadIdx.x; i < 1024; i += 256) lh[i] = 0;
  __syncthreads();
  uint32 pref = state[pass == 2 ? 0 : 2];
  int fsh = (pass == 2) ? 20 : 10;   // filter shift
  int bsh = (pass == 2) ? 10 : 0;    // bin shift
  int idx = blockIdx.x * 256 + threadIdx.x;
  int stride = gridDim.x * 256;
  for (int i = idx; i < NW / 4; i += stride) {
    uint4 v = wb[i];
    uint32 k;
    k = v.x & 0x7FFFFFFFu; if ((k >> fsh) == pref) atomicAdd(&lh[(k >> bsh) & 1023u], 1u);
    k = v.y & 0x7FFFFFFFu; if ((k >> fsh) == pref) atomicAdd(&lh[(k >> bsh) & 1023u], 1u);
    k = v.z & 0x7FFFFFFFu; if ((k >> fsh) == pref) atomicAdd(&lh[(k >> bsh) & 1023u], 1u);
    k = v.w & 0x7FFFFFFFu; if ((k >> fsh) == pref) atomicAdd(&lh[(k >> bsh) & 1023u], 1u);
  }
  __syncthreads();
  for (int i = threadIdx.x; i < 1024; i += 256) { uint32 c = lh[i]; if (c) atomicAdd(&hist[i], c); }
}

// one block of 256 threads: block-wide scan, find bin containing target rank
__global__ void scan_select(const uint32* __restrict__ hist, int nbins,
                            uint32* __restrict__ state, int pass) {
  int tid = threadIdx.x;
  int per = nbins >> 8;           // 8 (pass1) or 4 (pass2/3)
  uint32 loc[8];
  uint32 s = 0;
  int base = tid * per;
  for (int i = 0; i < per; i++) { loc[i] = hist[base + i]; s += loc[i]; }
  int lane = tid & 63, wid = tid >> 6;
  uint32 v = s;
  for (int d = 1; d < 64; d <<= 1) { uint32 o = __shfl_up(v, (unsigned)d); if (lane >= d) v += o; }
  __shared__ uint32 wtot[4];
  if (lane == 63) wtot[wid] = v;
  __syncthreads();
  uint32 woff = 0;
  for (int w = 0; w < wid; w++) woff += wtot[w];
  uint32 incl = v + woff;
  uint32 excl = incl - s;
  uint32 rank = (pass == 1) ? RANK1 : state[(pass == 2) ? 1 : 3];
  if (rank >= excl && rank < incl) {
    uint32 c = excl; int b = base;
    for (int i = 0; i < per; i++) {
      if (rank < c + loc[i]) { b = base + i; break; }
      c += loc[i];
    }
    uint32 rw = rank - c;
    if (pass == 1)      { state[0] = (uint32)b; state[1] = rw; }
    else if (pass == 2) { state[2] = (state[0] << 10) | (uint32)b; state[3] = rw; }
    else                { state[4] = (state[2] << 10) | (uint32)b; }   // v1 bit pattern
  }
}

// ---------- conversions ----------
__global__ void convert_w(const float4* __restrict__ w, const uint32* __restrict__ state,
                          uint4* __restrict__ out) {
  float thr = __uint_as_float(state[4]);
  int i = blockIdx.x * 256 + threadIdx.x;
  int stride = gridDim.x * 256;
  for (; i < NW / 8; i += stride) {
    float4 a = w[2 * i], b = w[2 * i + 1];
    float f[8] = {a.x, a.y, a.z, a.w, b.x, b.y, b.z, b.w};
    uint32 h[8];
#pragma unroll
    for (int j = 0; j < 8; j++) h[j] = (fabsf(f[j]) > thr) ? rne_bf16(f[j]) : 0u;
    uint4 o;
    o.x = h[0] | (h[1] << 16);
    o.y = h[2] | (h[3] << 16);
    o.z = h[4] | (h[5] << 16);
    o.w = h[6] | (h[7] << 16);
    out[i] = o;
  }
}

__global__ void convert_x(const float4* __restrict__ x, uint4* __restrict__ out) {
  int i = blockIdx.x * 256 + threadIdx.x;
  int stride = gridDim.x * 256;
  for (; i < NW / 8; i += stride) {
    float4 a = x[2 * i], b = x[2 * i + 1];
    uint4 o;
    o.x = rne_bf16(a.x) | (rne_bf16(a.y) << 16);
    o.y = rne_bf16(a.z) | (rne_bf16(a.w) << 16);
    o.z = rne_bf16(b.x) | (rne_bf16(b.y) << 16);
    o.w = rne_bf16(b.z) | (rne_bf16(b.w) << 16);
    out[i] = o;
  }
}

// ---------- GEMM: C[M,N] = Xb[M,K] * Wb[N,K]^T + bias, bf16 in / f32 out ----------
// 256x256 tile, BK=32, 8 waves (2x4), triple-buffered LDS, ONE phase + ONE barrier
// per K-tile. 12 frag reads/K-tile (B held across both MFMA halves). lgkmcnt(4)
// lets MFMA half 1 overlap the trailing frag reads and stage issue; vmcnt(4)
// counted (never 0). Waves drift within the phase -> LDS pipe overlaps matrix pipe.
#define TILES 128   // 4096 / 32

// stage one 256x32 bf16 panel (16KB) into LDS: 2 x global_load_lds(16B)/thread.
// LDS dest linear; swizzle applied to GLOBAL source k-chunk (rule 21).
__device__ __forceinline__ void stage16k(const ushort_t* __restrict__ G, int rowbase, int kt,
                                         ushort_t* lbase, int tid) {
#pragma unroll
  for (int j = 0; j < 2; j++) {
    int idx = j * 512 + tid;              // 16B-chunk index 0..1023
    int r = idx >> 2;                     // row 0..255
    int cl = (idx & 3) ^ ((r >> 1) & 3);  // logical k-chunk for this physical slot
    gload_lds16(G + (size_t)(rowbase + r) * D_IN + kt + cl * 8, lbase + idx * 8);
  }
}

__global__ __launch_bounds__(512, 2) void gemm_bt(const ushort_t* __restrict__ A,
                                                  const ushort_t* __restrict__ B,
                                                  const float* __restrict__ bias,
                                                  float* __restrict__ C) {
  extern __shared__ ushort_t lds[];   // 3 bufs x (A 8192 + B 8192) elems = 96KB

  int bid = blockIdx.x;                     // 256 blocks
  int swz = (bid & 7) * 32 + (bid >> 3);    // bijective XCD swizzle (256 % 8 == 0)
  int bm = swz >> 4;                        // 16 row-blocks
  int bn = swz & 15;                        // 16 col-blocks

  int tid  = threadIdx.x;
  int lane = tid & 63;
  int wave = tid >> 6;
  int wm = wave >> 2, wn = wave & 3;        // 2x4 wave grid: 128x64 per wave

  int l15  = lane & 15;
  int csel = (lane >> 4) ^ ((lane >> 1) & 3);  // swizzled k-chunk for frag reads

  const ushort_t* Ag = A;
  const ushort_t* Bg = B;

  f32x4 acc[8][4];
#pragma unroll
  for (int m = 0; m < 8; m++)
#pragma unroll
    for (int n = 0; n < 4; n++) acc[m][n] = (f32x4){0.f, 0.f, 0.f, 0.f};

  // prologue: stage tiles 0 and 1
  stage16k(Ag, bm * 256, 0,  lds,                 tid);
  stage16k(Bg, bn * 256, 0,  lds + 8192,          tid);
  stage16k(Ag, bm * 256, 32, lds + 16384,         tid);
  stage16k(Bg, bn * 256, 32, lds + 16384 + 8192,  tid);
  asm volatile("s_waitcnt vmcnt(4)" ::: "memory");   // tile 0 landed; tile 1 in flight
  asm volatile("s_barrier" ::: "memory");

  int ar = wm * 128 + l15;
  int br = wn * 64 + l15;

  int cur = 0, sd = 2;
  for (int t = 0; t < TILES; t++) {
    int u = t + 2; if (u > TILES - 1) u = TILES - 1;   // clamped prefetch keeps vmcnt uniform
    int kup = u * 32;
    ushort_t* sbase = lds + sd * 16384;
    const bf16x8* A8 = (const bf16x8*)(lds + cur * 16384);
    const bf16x8* B8 = A8 + 1024;

    bf16x8 af[8], bv[4];
    // group 1: frags for MFMA half 1
#pragma unroll
    for (int mm = 0; mm < 4; mm++) af[mm] = A8[(ar + mm * 16) * 4 + csel];
#pragma unroll
    for (int n = 0; n < 4; n++)    bv[n] = B8[(br + n * 16) * 4 + csel];
    __builtin_amdgcn_sched_barrier(0);   // pin issue order: group 1 before group 2
    // group 2: frags for MFMA half 2 + stage tile t+2
#pragma unroll
    for (int mm = 4; mm < 8; mm++) af[mm] = A8[(ar + mm * 16) * 4 + csel];
    stage16k(Ag, bm * 256, kup, sbase, tid);
    stage16k(Bg, bn * 256, kup, sbase + 8192, tid);

    asm volatile("s_waitcnt lgkmcnt(4)" ::: "memory");   // group 1 landed
    __builtin_amdgcn_sched_barrier(0);
    __builtin_amdgcn_s_setprio(1);
#pragma unroll
    for (int mm = 0; mm < 4; mm++)
#pragma unroll
      for (int n = 0; n < 4; n++)
        acc[mm][n] = __builtin_amdgcn_mfma_f32_16x16x32_bf16(af[mm], bv[n], acc[mm][n], 0, 0, 0);
    __builtin_amdgcn_s_setprio(0);

    asm volatile("s_waitcnt lgkmcnt(0)" ::: "memory");   // group 2 landed
    __builtin_amdgcn_sched_barrier(0);
    __builtin_amdgcn_s_setprio(1);
#pragma unroll
    for (int mm = 4; mm < 8; mm++)
#pragma unroll
      for (int n = 0; n < 4; n++)
        acc[mm][n] = __builtin_amdgcn_mfma_f32_16x16x32_bf16(af[mm], bv[n], acc[mm][n], 0, 0, 0);
    __builtin_amdgcn_s_setprio(0);
    __builtin_amdgcn_sched_barrier(0);

    asm volatile("s_waitcnt vmcnt(4)" ::: "memory");     // tile t+1's 4 loads done; t+2 in flight
    asm volatile("s_barrier" ::: "memory");              // publish buf t+1, protect buf sd

    cur = (cur == 2) ? 0 : cur + 1;
    sd  = (sd  == 2) ? 0 : sd + 1;
  }

  int orow0 = bm * 256 + wm * 128 + (lane >> 4) * 4;
  int ocol0 = bn * 256 + wn * 64 + l15;
#pragma unroll
  for (int n = 0; n < 4; n++) {
    float bv2 = bias[ocol0 + n * 16];
#pragma unroll
    for (int m = 0; m < 8; m++) {
#pragma unroll
      for (int r = 0; r < 4; r++) {
        C[(size_t)(orow0 + m * 16 + r) * D_OUT + ocol0 + n * 16] = acc[m][n][r] + bv2;
      }
    }
  }
}

// ---------- launch ----------
extern "C" void kernel_launch(void* const* d_in, const int* in_sizes, int n_in,
                              void* d_out, int out_size, void* d_ws, size_t ws_size,
                              hipStream_t stream) {
  const float* x = (const float*)d_in[0];
  const float* w = (const float*)d_in[1];
  const float* bias = (const float*)d_in[2];
  float* out = (float*)d_out;

  char* ws = (char*)d_ws;
  uint32* hist1 = (uint32*)ws;                 // 2048 bins
  uint32* hist2 = (uint32*)(ws + 8192);        // 1024 bins
  uint32* hist3 = (uint32*)(ws + 12288);       // 1024 bins
  uint32* state = (uint32*)(ws + 16384);       // 16 slots
  ushort_t* Xb = (ushort_t*)(ws + 65536);
  ushort_t* Wb = (ushort_t*)(ws + 65536 + (size_t)NW * 2);

  hipMemsetAsync(d_ws, 0, 16448, stream);

  hist_pass1<<<2048, 256, 0, stream>>>((const uint4*)w, hist1);
  scan_select<<<1, 256, 0, stream>>>(hist1, 2048, state, 1);
  hist_pass23<<<2048, 256, 0, stream>>>((const uint4*)w, state, hist2, 2);
  scan_select<<<1, 256, 0, stream>>>(hist2, 1024, state, 2);
  hist_pass23<<<2048, 256, 0, stream>>>((const uint4*)w, state, hist3, 3);
  scan_select<<<1, 256, 0, stream>>>(hist3, 1024, state, 3);

  convert_w<<<2048, 256, 0, stream>>>((const float4*)w, state, (uint4*)Wb);
  convert_x<<<2048, 256, 0, stream>>>((const float4*)x, (uint4*)Xb);

  gemm_bt<<<256, 512, 98304, stream>>>(Xb, Wb, bias, out);
}

// Round 4
// 242.098 us; speedup vs baseline: 1.3719x; 1.0653x over previous
//
#include <hip/hip_runtime.h>
#include <stdint.h>

#define D_IN   4096
#define D_OUT  4096
#define NTOK   4096
#define NW     (D_OUT * D_IN)          // 16777216
#define RANK1  15099493u               // floor(0.9f * (NW-1)) as jax computes in f32

typedef unsigned int  uint32;
typedef unsigned short ushort_t;
typedef float  f32x4  __attribute__((ext_vector_type(4)));
typedef __bf16 bf16x8 __attribute__((ext_vector_type(8)));

// ---------- helpers ----------
__device__ __forceinline__ uint32 rne_bf16(float f) {
  uint32 u = __float_as_uint(f);
  return (u + 0x7FFFu + ((u >> 16) & 1u)) >> 16;
}

__device__ __forceinline__ void gload_lds16(const void* g, void* l) {
  __builtin_amdgcn_global_load_lds((__attribute__((address_space(1))) void*)(g),
                                   (__attribute__((address_space(3))) void*)(l), 16, 0, 0);
}

// block-redundant select: find bin containing `rank` in NB-bin global histogram.
// All 256 threads participate; res[0]=bin, res[1]=rank_within. Cheap (L2 reads).
template <int NB>
__device__ __forceinline__ void dsel(const uint32* __restrict__ h, uint32 rank,
                                     uint32* res, uint32* wtot) {
  constexpr int PER = NB >> 8;
  int tid = threadIdx.x;
  int lane = tid & 63, wid = tid >> 6;
  uint32 loc[PER];
  uint32 s = 0;
  int base = tid * PER;
#pragma unroll
  for (int i = 0; i < PER; i++) { loc[i] = h[base + i]; s += loc[i]; }
  uint32 v = s;
  for (int d = 1; d < 64; d <<= 1) { uint32 o = __shfl_up(v, (unsigned)d); if (lane >= d) v += o; }
  if (lane == 63) wtot[wid] = v;
  __syncthreads();
  uint32 woff = 0;
  for (int w = 0; w < wid; w++) woff += wtot[w];
  uint32 incl = v + woff, excl = incl - s;
  if (rank >= excl && rank < incl) {
    uint32 c = excl;
#pragma unroll
    for (int i = 0; i < PER; i++) {
      if (rank < c + loc[i]) { res[0] = (uint32)(base + i); res[1] = rank - c; break; }
      c += loc[i];
    }
  }
  __syncthreads();
}

// ---------- K1: hist pass 1 (blocks 0..2047) fused with convert_x (blocks 2048..3071) ----------
__global__ void k1_hist1_convx(const uint4* __restrict__ wb, uint32* __restrict__ hist,
                               const float4* __restrict__ x, uint4* __restrict__ xout) {
  __shared__ uint32 lh[4][2048];
  if (blockIdx.x < 2048) {
    for (int i = threadIdx.x; i < 8192; i += 256) ((uint32*)lh)[i] = 0;
    __syncthreads();
    int wid = threadIdx.x >> 6;
    int idx = blockIdx.x * 256 + threadIdx.x;
    for (int i = idx; i < NW / 4; i += 2048 * 256) {
      uint4 v = wb[i];
      atomicAdd(&lh[wid][(v.x & 0x7FFFFFFFu) >> 20], 1u);
      atomicAdd(&lh[wid][(v.y & 0x7FFFFFFFu) >> 20], 1u);
      atomicAdd(&lh[wid][(v.z & 0x7FFFFFFFu) >> 20], 1u);
      atomicAdd(&lh[wid][(v.w & 0x7FFFFFFFu) >> 20], 1u);
    }
    __syncthreads();
    for (int i = threadIdx.x; i < 2048; i += 256) {
      uint32 c = lh[0][i] + lh[1][i] + lh[2][i] + lh[3][i];
      if (c) atomicAdd(&hist[i], c);
    }
  } else {
    int i = (blockIdx.x - 2048) * 256 + threadIdx.x;
    for (; i < NW / 8; i += 1024 * 256) {
      float4 a = x[2 * i], b = x[2 * i + 1];
      uint4 o;
      o.x = rne_bf16(a.x) | (rne_bf16(a.y) << 16);
      o.y = rne_bf16(a.z) | (rne_bf16(a.w) << 16);
      o.z = rne_bf16(b.x) | (rne_bf16(b.y) << 16);
      o.w = rne_bf16(b.z) | (rne_bf16(b.w) << 16);
      xout[i] = o;
    }
  }
}

// ---------- K2: hist pass 2 (self-selects prefix from hist1) ----------
__global__ void k2_hist2(const uint4* __restrict__ wb, const uint32* __restrict__ hist1,
                         uint32* __restrict__ hist2) {
  __shared__ uint32 lh[1024];
  __shared__ uint32 res1[2], wt[4];
  for (int i = threadIdx.x; i < 1024; i += 256) lh[i] = 0;
  dsel<2048>(hist1, RANK1, res1, wt);
  uint32 pref = res1[0];
  int idx = blockIdx.x * 256 + threadIdx.x;
  for (int i = idx; i < NW / 4; i += 2048 * 256) {
    uint4 v = wb[i];
    uint32 k;
    k = v.x & 0x7FFFFFFFu; if ((k >> 20) == pref) atomicAdd(&lh[(k >> 10) & 1023u], 1u);
    k = v.y & 0x7FFFFFFFu; if ((k >> 20) == pref) atomicAdd(&lh[(k >> 10) & 1023u], 1u);
    k = v.z & 0x7FFFFFFFu; if ((k >> 20) == pref) atomicAdd(&lh[(k >> 10) & 1023u], 1u);
    k = v.w & 0x7FFFFFFFu; if ((k >> 20) == pref) atomicAdd(&lh[(k >> 10) & 1023u], 1u);
  }
  __syncthreads();
  for (int i = threadIdx.x; i < 1024; i += 256) { uint32 c = lh[i]; if (c) atomicAdd(&hist2[i], c); }
}

// ---------- K3: hist pass 3 ----------
__global__ void k3_hist3(const uint4* __restrict__ wb, const uint32* __restrict__ hist1,
                         const uint32* __restrict__ hist2, uint32* __restrict__ hist3) {
  __shared__ uint32 lh[1024];
  __shared__ uint32 res1[2], res2[2], wt[4];
  for (int i = threadIdx.x; i < 1024; i += 256) lh[i] = 0;
  dsel<2048>(hist1, RANK1, res1, wt);
  dsel<1024>(hist2, res1[1], res2, wt);
  uint32 pref = (res1[0] << 10) | res2[0];
  int idx = blockIdx.x * 256 + threadIdx.x;
  for (int i = idx; i < NW / 4; i += 2048 * 256) {
    uint4 v = wb[i];
    uint32 k;
    k = v.x & 0x7FFFFFFFu; if ((k >> 10) == pref) atomicAdd(&lh[k & 1023u], 1u);
    k = v.y & 0x7FFFFFFFu; if ((k >> 10) == pref) atomicAdd(&lh[k & 1023u], 1u);
    k = v.z & 0x7FFFFFFFu; if ((k >> 10) == pref) atomicAdd(&lh[k & 1023u], 1u);
    k = v.w & 0x7FFFFFFFu; if ((k >> 10) == pref) atomicAdd(&lh[k & 1023u], 1u);
  }
  __syncthreads();
  for (int i = threadIdx.x; i < 1024; i += 256) { uint32 c = lh[i]; if (c) atomicAdd(&hist3[i], c); }
}

// ---------- K4: final select + prune + bf16-convert W ----------
__global__ void k4_convw(const float4* __restrict__ w, const uint32* __restrict__ hist1,
                         const uint32* __restrict__ hist2, const uint32* __restrict__ hist3,
                         uint4* __restrict__ out) {
  __shared__ uint32 res1[2], res2[2], res3[2], wt[4];
  dsel<2048>(hist1, RANK1, res1, wt);
  dsel<1024>(hist2, res1[1], res2, wt);
  dsel<1024>(hist3, res2[1], res3, wt);
  float thr = __uint_as_float((res1[0] << 20) | (res2[0] << 10) | res3[0]);
  int i = blockIdx.x * 256 + threadIdx.x;
  for (; i < NW / 8; i += 2048 * 256) {
    float4 a = w[2 * i], b = w[2 * i + 1];
    float f[8] = {a.x, a.y, a.z, a.w, b.x, b.y, b.z, b.w};
    uint32 h[8];
#pragma unroll
    for (int j = 0; j < 8; j++) h[j] = (fabsf(f[j]) > thr) ? rne_bf16(f[j]) : 0u;
    uint4 o;
    o.x = h[0] | (h[1] << 16);
    o.y = h[2] | (h[3] << 16);
    o.z = h[4] | (h[5] << 16);
    o.w = h[6] | (h[7] << 16);
    out[i] = o;
  }
}

// ---------- GEMM: C[M,N] = Xb[M,K] * Wb[N,K]^T + bias, bf16 in / f32 out ----------
// 256x256 tile, BK=32, 8 waves (2x4), triple-buffered LDS. Per K-tile: all 12
// frag reads issued up front, then 4x8-MFMA bursts gated by lgkmcnt(6/4/2/0) so
// LDS drains under MFMA. Tile-end barrier sits BEFORE the last burst (operands
// already in regs) so next tile's reads overlap the tail MFMAs. vmcnt(4) counted.
#define TILES 128   // 4096 / 32

__global__ __launch_bounds__(512, 2) void gemm_bt(const ushort_t* __restrict__ A,
                                                  const ushort_t* __restrict__ B,
                                                  const float* __restrict__ bias,
                                                  float* __restrict__ C) {
  extern __shared__ ushort_t lds[];   // 3 bufs x 32KB = 96KB

  int bid = blockIdx.x;                     // 256 blocks
  int swz = (bid & 7) * 32 + (bid >> 3);    // bijective XCD swizzle (256 % 8 == 0)
  int bm = swz >> 4;
  int bn = swz & 15;

  int tid  = threadIdx.x;
  int lane = tid & 63;
  int wave = tid >> 6;
  int wm = wave >> 2, wn = wave & 3;        // 2x4 wave grid: 128x64 per wave

  int l15  = lane & 15;
  int csel = (lane >> 4) ^ ((lane >> 1) & 3);  // swizzled k-chunk for frag reads

  // staging geometry: chunk idx covers lds[idx*8 .. idx*8+8); row=idx>>2, swizzled k-chunk
  int idx0 = tid, idx1 = 512 + tid;
  int sr0 = idx0 >> 2, scl0 = (idx0 & 3) ^ ((sr0 >> 1) & 3);
  int sr1 = idx1 >> 2, scl1 = (idx1 & 3) ^ ((sr1 >> 1) & 3);
  int ld0 = idx0 * 8, ld1 = idx1 * 8;
  const ushort_t* pA0 = A + (size_t)(bm * 256 + sr0) * D_IN + scl0 * 8;
  const ushort_t* pA1 = A + (size_t)(bm * 256 + sr1) * D_IN + scl1 * 8;
  const ushort_t* pB0 = B + (size_t)(bn * 256 + sr0) * D_IN + scl0 * 8;
  const ushort_t* pB1 = B + (size_t)(bn * 256 + sr1) * D_IN + scl1 * 8;

  f32x4 acc[8][4];
#pragma unroll
  for (int m = 0; m < 8; m++)
#pragma unroll
    for (int n = 0; n < 4; n++) acc[m][n] = (f32x4){0.f, 0.f, 0.f, 0.f};

  // prologue: stage tiles 0 and 1
  gload_lds16(pA0,      lds + ld0);         gload_lds16(pA1,      lds + ld1);
  gload_lds16(pB0,      lds + 8192 + ld0);  gload_lds16(pB1,      lds + 8192 + ld1);
  gload_lds16(pA0 + 32, lds + 16384 + ld0); gload_lds16(pA1 + 32, lds + 16384 + ld1);
  gload_lds16(pB0 + 32, lds + 24576 + ld0); gload_lds16(pB1 + 32, lds + 24576 + ld1);
  pA0 += 64; pA1 += 64; pB0 += 64; pB1 += 64;   // in-loop staging starts at tile 2
  asm volatile("s_waitcnt vmcnt(4)" ::: "memory");
  asm volatile("s_barrier" ::: "memory");

  int ar = wm * 128 + l15;
  int br = wn * 64 + l15;

  int cur = 0, sd = 2;
  for (int t = 0; t < TILES; t++) {
    ushort_t* sbase = lds + sd * 16384;
    const bf16x8* A8 = (const bf16x8*)(lds + cur * 16384);
    const bf16x8* B8 = A8 + 1024;

    bf16x8 bv0, bv1, bv2, bv3, a0, a1, a2, a3, a4, a5, a6, a7;
    // R1: 6 reads
    bv0 = B8[(br +  0) * 4 + csel];
    bv1 = B8[(br + 16) * 4 + csel];
    bv2 = B8[(br + 32) * 4 + csel];
    bv3 = B8[(br + 48) * 4 + csel];
    a0  = A8[(ar +  0) * 4 + csel];
    a1  = A8[(ar + 16) * 4 + csel];
    __builtin_amdgcn_sched_barrier(0);
    // R2: 6 reads
    a2  = A8[(ar + 32) * 4 + csel];
    a3  = A8[(ar + 48) * 4 + csel];
    a4  = A8[(ar + 64) * 4 + csel];
    a5  = A8[(ar + 80) * 4 + csel];
    a6  = A8[(ar + 96) * 4 + csel];
    a7  = A8[(ar + 112) * 4 + csel];
    __builtin_amdgcn_sched_barrier(0);
    // stage tile t+2 (4 vm loads)
    gload_lds16(pA0, sbase + ld0);
    gload_lds16(pA1, sbase + ld1);
    gload_lds16(pB0, sbase + 8192 + ld0);
    gload_lds16(pB1, sbase + 8192 + ld1);
    __builtin_amdgcn_sched_barrier(0);

    asm volatile("s_waitcnt lgkmcnt(6)" ::: "memory");   // R1 landed
    __builtin_amdgcn_sched_barrier(0);
    __builtin_amdgcn_s_setprio(1);
#pragma unroll
    for (int n = 0; n < 4; n++) {
      bf16x8 bvv = (n == 0) ? bv0 : (n == 1) ? bv1 : (n == 2) ? bv2 : bv3;
      acc[0][n] = __builtin_amdgcn_mfma_f32_16x16x32_bf16(a0, bvv, acc[0][n], 0, 0, 0);
      acc[1][n] = __builtin_amdgcn_mfma_f32_16x16x32_bf16(a1, bvv, acc[1][n], 0, 0, 0);
    }
    __builtin_amdgcn_s_setprio(0);

    asm volatile("s_waitcnt lgkmcnt(4)" ::: "memory");
    __builtin_amdgcn_sched_barrier(0);
    __builtin_amdgcn_s_setprio(1);
#pragma unroll
    for (int n = 0; n < 4; n++) {
      bf16x8 bvv = (n == 0) ? bv0 : (n == 1) ? bv1 : (n == 2) ? bv2 : bv3;
      acc[2][n] = __builtin_amdgcn_mfma_f32_16x16x32_bf16(a2, bvv, acc[2][n], 0, 0, 0);
      acc[3][n] = __builtin_amdgcn_mfma_f32_16x16x32_bf16(a3, bvv, acc[3][n], 0, 0, 0);
    }
    __builtin_amdgcn_s_setprio(0);

    asm volatile("s_waitcnt lgkmcnt(2)" ::: "memory");
    __builtin_amdgcn_sched_barrier(0);
    __builtin_amdgcn_s_setprio(1);
#pragma unroll
    for (int n = 0; n < 4; n++) {
      bf16x8 bvv = (n == 0) ? bv0 : (n == 1) ? bv1 : (n == 2) ? bv2 : bv3;
      acc[4][n] = __builtin_amdgcn_mfma_f32_16x16x32_bf16(a4, bvv, acc[4][n], 0, 0, 0);
      acc[5][n] = __builtin_amdgcn_mfma_f32_16x16x32_bf16(a5, bvv, acc[5][n], 0, 0, 0);
    }
    __builtin_amdgcn_s_setprio(0);

    // my LDS reads done + tile t+1 data landed -> release buffers early; the
    // last 8 MFMAs run on registers and overlap next tile's frag reads.
    asm volatile("s_waitcnt vmcnt(4) lgkmcnt(0)" ::: "memory");
    asm volatile("s_barrier" ::: "memory");
    __builtin_amdgcn_sched_barrier(0);
    __builtin_amdgcn_s_setprio(1);
#pragma unroll
    for (int n = 0; n < 4; n++) {
      bf16x8 bvv = (n == 0) ? bv0 : (n == 1) ? bv1 : (n == 2) ? bv2 : bv3;
      acc[6][n] = __builtin_amdgcn_mfma_f32_16x16x32_bf16(a6, bvv, acc[6][n], 0, 0, 0);
      acc[7][n] = __builtin_amdgcn_mfma_f32_16x16x32_bf16(a7, bvv, acc[7][n], 0, 0, 0);
    }
    __builtin_amdgcn_s_setprio(0);

    if (t < TILES - 3) { pA0 += 32; pA1 += 32; pB0 += 32; pB1 += 32; }
    cur = (cur == 2) ? 0 : cur + 1;
    sd  = (sd  == 2) ? 0 : sd + 1;
  }

  int orow0 = bm * 256 + wm * 128 + (lane >> 4) * 4;
  int ocol0 = bn * 256 + wn * 64 + l15;
#pragma unroll
  for (int n = 0; n < 4; n++) {
    float bv2 = bias[ocol0 + n * 16];
#pragma unroll
    for (int m = 0; m < 8; m++) {
#pragma unroll
      for (int r = 0; r < 4; r++) {
        C[(size_t)(orow0 + m * 16 + r) * D_OUT + ocol0 + n * 16] = acc[m][n][r] + bv2;
      }
    }
  }
}

// ---------- launch ----------
extern "C" void kernel_launch(void* const* d_in, const int* in_sizes, int n_in,
                              void* d_out, int out_size, void* d_ws, size_t ws_size,
                              hipStream_t stream) {
  const float* x = (const float*)d_in[0];
  const float* w = (const float*)d_in[1];
  const float* bias = (const float*)d_in[2];
  float* out = (float*)d_out;

  char* ws = (char*)d_ws;
  uint32* hist1 = (uint32*)ws;                 // 2048 bins
  uint32* hist2 = (uint32*)(ws + 8192);        // 1024 bins
  uint32* hist3 = (uint32*)(ws + 12288);       // 1024 bins
  ushort_t* Xb = (ushort_t*)(ws + 65536);
  ushort_t* Wb = (ushort_t*)(ws + 65536 + (size_t)NW * 2);

  hipMemsetAsync(d_ws, 0, 16384, stream);

  k1_hist1_convx<<<3072, 256, 0, stream>>>((const uint4*)w, hist1, (const float4*)x, (uint4*)Xb);
  k2_hist2<<<2048, 256, 0, stream>>>((const uint4*)w, hist1, hist2);
  k3_hist3<<<2048, 256, 0, stream>>>((const uint4*)w, hist1, hist2, hist3);
  k4_convw<<<2048, 256, 0, stream>>>((const float4*)w, hist1, hist2, hist3, (uint4*)Wb);

  gemm_bt<<<256, 512, 98304, stream>>>(Xb, Wb, bias, out);
}

// Round 5
// 212.527 us; speedup vs baseline: 1.5628x; 1.1391x over previous
//
#include <hip/hip_runtime.h>
#include <stdint.h>

#define D_IN   4096
#define D_OUT  4096
#define NTOK   4096
#define NW     (D_OUT * D_IN)          // 16777216
#define RANK1  15099493u               // floor(0.9f * (NW-1)) as jax computes in f32
#define CAP    1500000                 // candidate list capacity (expected ~450K)

typedef unsigned int  uint32;
typedef unsigned short ushort_t;
typedef float  f32x4  __attribute__((ext_vector_type(4)));
typedef __bf16 bf16x8 __attribute__((ext_vector_type(8)));

// ---------- helpers ----------
__device__ __forceinline__ uint32 rne_bf16(float f) {
  uint32 u = __float_as_uint(f);
  return (u + 0x7FFFu + ((u >> 16) & 1u)) >> 16;
}

__device__ __forceinline__ void gload_lds16(const void* g, void* l) {
  __builtin_amdgcn_global_load_lds((__attribute__((address_space(1))) void*)(g),
                                   (__attribute__((address_space(3))) void*)(l), 16, 0, 0);
}

// block-redundant select: find bin containing `rank` in NB-bin global histogram.
template <int NB>
__device__ __forceinline__ void dsel(const uint32* __restrict__ h, uint32 rank,
                                     uint32* res, uint32* wtot) {
  constexpr int PER = NB >> 8;
  int tid = threadIdx.x;
  int lane = tid & 63, wid = tid >> 6;
  uint32 loc[PER];
  uint32 s = 0;
  int base = tid * PER;
#pragma unroll
  for (int i = 0; i < PER; i++) { loc[i] = h[base + i]; s += loc[i]; }
  uint32 v = s;
  for (int d = 1; d < 64; d <<= 1) { uint32 o = __shfl_up(v, (unsigned)d); if (lane >= d) v += o; }
  if (lane == 63) wtot[wid] = v;
  __syncthreads();
  uint32 woff = 0;
  for (int w = 0; w < wid; w++) woff += wtot[w];
  uint32 incl = v + woff, excl = incl - s;
  if (rank >= excl && rank < incl) {
    uint32 c = excl;
#pragma unroll
    for (int i = 0; i < PER; i++) {
      if (rank < c + loc[i]) { res[0] = (uint32)(base + i); res[1] = rank - c; break; }
      c += loc[i];
    }
  }
  __syncthreads();
}

// ---------- K1: hist pass 1 (blocks 0..2047) fused with convert_x (blocks 2048..3071) ----------
__global__ void k1_hist1_convx(const uint4* __restrict__ wb, uint32* __restrict__ hist,
                               const float4* __restrict__ x, uint4* __restrict__ xout) {
  __shared__ uint32 lh[4][2048];
  if (blockIdx.x < 2048) {
    for (int i = threadIdx.x; i < 8192; i += 256) ((uint32*)lh)[i] = 0;
    __syncthreads();
    int wid = threadIdx.x >> 6;
    int idx = blockIdx.x * 256 + threadIdx.x;
    for (int i = idx; i < NW / 4; i += 2048 * 256) {
      uint4 v = wb[i];
      atomicAdd(&lh[wid][(v.x & 0x7FFFFFFFu) >> 20], 1u);
      atomicAdd(&lh[wid][(v.y & 0x7FFFFFFFu) >> 20], 1u);
      atomicAdd(&lh[wid][(v.z & 0x7FFFFFFFu) >> 20], 1u);
      atomicAdd(&lh[wid][(v.w & 0x7FFFFFFFu) >> 20], 1u);
    }
    __syncthreads();
    for (int i = threadIdx.x; i < 2048; i += 256) {
      uint32 c = lh[0][i] + lh[1][i] + lh[2][i] + lh[3][i];
      if (c) atomicAdd(&hist[i], c);
    }
  } else {
    int i = (blockIdx.x - 2048) * 256 + threadIdx.x;
    for (; i < NW / 8; i += 1024 * 256) {
      float4 a = x[2 * i], b = x[2 * i + 1];
      uint4 o;
      o.x = rne_bf16(a.x) | (rne_bf16(a.y) << 16);
      o.y = rne_bf16(a.z) | (rne_bf16(a.w) << 16);
      o.z = rne_bf16(b.x) | (rne_bf16(b.y) << 16);
      o.w = rne_bf16(b.z) | (rne_bf16(b.w) << 16);
      xout[i] = o;
    }
  }
}

// ---------- K2: decide + convert W + compact threshold-bin candidates (ONE pass) ----------
__global__ void k2_decide(const float4* __restrict__ w, const uint32* __restrict__ hist1,
                          uint4* __restrict__ out, uint2* __restrict__ cand,
                          uint32* __restrict__ cnt) {
  __shared__ uint32 res1[2], wt[4];
  __shared__ uint32 lcnt, lbase;
  __shared__ uint2 lbuf[3072];
  if (threadIdx.x == 0) lcnt = 0;
  dsel<2048>(hist1, RANK1, res1, wt);          // syncs internally
  uint32 bstar = res1[0];
  int i = blockIdx.x * 256 + threadIdx.x;
  for (; i < NW / 8; i += 512 * 256) {
    float4 a = w[2 * i], b = w[2 * i + 1];
    float f[8] = {a.x, a.y, a.z, a.w, b.x, b.y, b.z, b.w};
    uint32 h[8];
#pragma unroll
    for (int j = 0; j < 8; j++) {
      uint32 bits = __float_as_uint(f[j]);
      uint32 bin = (bits & 0x7FFFFFFFu) >> 20;
      h[j] = (bin > bstar) ? rne_bf16(f[j]) : 0u;
      if (bin == bstar) {
        uint32 p = atomicAdd(&lcnt, 1u);
        if (p < 3072) lbuf[p] = make_uint2((uint32)(8 * i + j), bits);
      }
    }
    uint4 o;
    o.x = h[0] | (h[1] << 16);
    o.y = h[2] | (h[3] << 16);
    o.z = h[4] | (h[5] << 16);
    o.w = h[6] | (h[7] << 16);
    out[i] = o;
  }
  __syncthreads();
  if (threadIdx.x == 0) lbase = atomicAdd(cnt, lcnt);
  __syncthreads();
  for (uint32 p = threadIdx.x; p < lcnt && p < 3072; p += 256) {
    uint32 g = lbase + p;
    if (g < CAP) cand[g] = lbuf[p];
  }
}

// ---------- S1: 1024-bin hist over candidate mag bits [19:10] ----------
__global__ void s1_hist(const uint2* __restrict__ cand, const uint32* __restrict__ cnt,
                        uint32* __restrict__ hs1) {
  __shared__ uint32 lh[1024];
  for (int i = threadIdx.x; i < 1024; i += 256) lh[i] = 0;
  __syncthreads();
  uint32 n = *cnt; if (n > CAP) n = CAP;
  for (uint32 i = blockIdx.x * 256 + threadIdx.x; i < n; i += gridDim.x * 256) {
    uint32 mag = cand[i].y & 0x7FFFFFFFu;
    atomicAdd(&lh[(mag >> 10) & 1023u], 1u);
  }
  __syncthreads();
  for (int i = threadIdx.x; i < 1024; i += 256) if (lh[i]) atomicAdd(&hs1[i], lh[i]);
}

// ---------- S2: filter on bits[19:10], hist bits [9:0] ----------
__global__ void s2_hist(const uint2* __restrict__ cand, const uint32* __restrict__ cnt,
                        const uint32* __restrict__ hist1, const uint32* __restrict__ hs1,
                        uint32* __restrict__ hs2) {
  __shared__ uint32 lh[1024];
  __shared__ uint32 res1[2], res2[2], wt[4];
  for (int i = threadIdx.x; i < 1024; i += 256) lh[i] = 0;
  dsel<2048>(hist1, RANK1, res1, wt);
  dsel<1024>(hs1, res1[1], res2, wt);
  uint32 b2 = res2[0];
  uint32 n = *cnt; if (n > CAP) n = CAP;
  for (uint32 i = blockIdx.x * 256 + threadIdx.x; i < n; i += gridDim.x * 256) {
    uint32 mag = cand[i].y & 0x7FFFFFFFu;
    if (((mag >> 10) & 1023u) == b2) atomicAdd(&lh[mag & 1023u], 1u);
  }
  __syncthreads();
  for (int i = threadIdx.x; i < 1024; i += 256) if (lh[i]) atomicAdd(&hs2[i], lh[i]);
}

// ---------- K5: final threshold, fix up kept candidates ----------
__global__ void k5_fixup(const uint2* __restrict__ cand, const uint32* __restrict__ cnt,
                         const uint32* __restrict__ hist1, const uint32* __restrict__ hs1,
                         const uint32* __restrict__ hs2, ushort_t* __restrict__ wb) {
  __shared__ uint32 res1[2], res2[2], res3[2], wt[4];
  dsel<2048>(hist1, RANK1, res1, wt);
  dsel<1024>(hs1, res1[1], res2, wt);
  dsel<1024>(hs2, res2[1], res3, wt);
  uint32 thr_mag = (res1[0] << 20) | (res2[0] << 10) | res3[0];
  uint32 n = *cnt; if (n > CAP) n = CAP;
  for (uint32 i = blockIdx.x * 256 + threadIdx.x; i < n; i += gridDim.x * 256) {
    uint2 c = cand[i];
    uint32 mag = c.y & 0x7FFFFFFFu;
    if (mag > thr_mag) wb[c.x] = (ushort_t)rne_bf16(__uint_as_float(c.y));
  }
}

// ---------- GEMM: C[M,N] = Xb[M,K] * Wb[N,K]^T + bias ----------
// 256x256 tile, BK=32, 8 waves (2x4), QUAD-buffered LDS (128KB), stage 3-ahead.
// Software-pipelined frag reads: each MFMA burst runs with 4-8 ds_reads in
// flight for the NEXT half-tile. One barrier, one vmcnt(4), per K-tile.
#define TILES 128

#define MF16(AF, BF, MO)                                                                          \
  acc[(MO)+0][0] = __builtin_amdgcn_mfma_f32_16x16x32_bf16(AF[0], BF[0], acc[(MO)+0][0], 0,0,0);  \
  acc[(MO)+0][1] = __builtin_amdgcn_mfma_f32_16x16x32_bf16(AF[0], BF[1], acc[(MO)+0][1], 0,0,0);  \
  acc[(MO)+0][2] = __builtin_amdgcn_mfma_f32_16x16x32_bf16(AF[0], BF[2], acc[(MO)+0][2], 0,0,0);  \
  acc[(MO)+0][3] = __builtin_amdgcn_mfma_f32_16x16x32_bf16(AF[0], BF[3], acc[(MO)+0][3], 0,0,0);  \
  acc[(MO)+1][0] = __builtin_amdgcn_mfma_f32_16x16x32_bf16(AF[1], BF[0], acc[(MO)+1][0], 0,0,0);  \
  acc[(MO)+1][1] = __builtin_amdgcn_mfma_f32_16x16x32_bf16(AF[1], BF[1], acc[(MO)+1][1], 0,0,0);  \
  acc[(MO)+1][2] = __builtin_amdgcn_mfma_f32_16x16x32_bf16(AF[1], BF[2], acc[(MO)+1][2], 0,0,0);  \
  acc[(MO)+1][3] = __builtin_amdgcn_mfma_f32_16x16x32_bf16(AF[1], BF[3], acc[(MO)+1][3], 0,0,0);  \
  acc[(MO)+2][0] = __builtin_amdgcn_mfma_f32_16x16x32_bf16(AF[2], BF[0], acc[(MO)+2][0], 0,0,0);  \
  acc[(MO)+2][1] = __builtin_amdgcn_mfma_f32_16x16x32_bf16(AF[2], BF[1], acc[(MO)+2][1], 0,0,0);  \
  acc[(MO)+2][2] = __builtin_amdgcn_mfma_f32_16x16x32_bf16(AF[2], BF[2], acc[(MO)+2][2], 0,0,0);  \
  acc[(MO)+2][3] = __builtin_amdgcn_mfma_f32_16x16x32_bf16(AF[2], BF[3], acc[(MO)+2][3], 0,0,0);  \
  acc[(MO)+3][0] = __builtin_amdgcn_mfma_f32_16x16x32_bf16(AF[3], BF[0], acc[(MO)+3][0], 0,0,0);  \
  acc[(MO)+3][1] = __builtin_amdgcn_mfma_f32_16x16x32_bf16(AF[3], BF[1], acc[(MO)+3][1], 0,0,0);  \
  acc[(MO)+3][2] = __builtin_amdgcn_mfma_f32_16x16x32_bf16(AF[3], BF[2], acc[(MO)+3][2], 0,0,0);  \
  acc[(MO)+3][3] = __builtin_amdgcn_mfma_f32_16x16x32_bf16(AF[3], BF[3], acc[(MO)+3][3], 0,0,0);

// Body T: computes half2(T) then half1(T+1). S = T&1, SN = (T+1)&1 (literals).
#define GBODY(T, S, SN)                                                        \
  {                                                                            \
    const bf16x8* A8n = (const bf16x8*)(lds + (((T) + 1) & 3) * 16384);        \
    const bf16x8* B8n = A8n + 1024;                                            \
    bv[SN][0]  = B8n[(br +  0) * 4 + csel];                                    \
    bv[SN][1]  = B8n[(br + 16) * 4 + csel];                                    \
    bv[SN][2]  = B8n[(br + 32) * 4 + csel];                                    \
    bv[SN][3]  = B8n[(br + 48) * 4 + csel];                                    \
    a03[SN][0] = A8n[(ar +  0) * 4 + csel];                                    \
    a03[SN][1] = A8n[(ar + 16) * 4 + csel];                                    \
    a03[SN][2] = A8n[(ar + 32) * 4 + csel];                                    \
    a03[SN][3] = A8n[(ar + 48) * 4 + csel];                                    \
    __builtin_amdgcn_sched_barrier(0);                                         \
    ushort_t* sb = lds + (((T) + 3) & 3) * 16384;                              \
    gload_lds16(pA0, sb + ld0);                                                \
    gload_lds16(pA1, sb + ld1);                                                \
    gload_lds16(pB0, sb + 8192 + ld0);                                         \
    gload_lds16(pB1, sb + 8192 + ld1);                                         \
    __builtin_amdgcn_sched_barrier(0);                                         \
    asm volatile("s_waitcnt lgkmcnt(8)" ::: "memory");                         \
    __builtin_amdgcn_sched_barrier(0);                                         \
    __builtin_amdgcn_s_setprio(1);                                             \
    MF16(a47[S], bv[S], 4)                                                     \
    __builtin_amdgcn_s_setprio(0);                                             \
    __builtin_amdgcn_sched_barrier(0);                                         \
    a47[SN][0] = A8n[(ar +  64) * 4 + csel];                                   \
    a47[SN][1] = A8n[(ar +  80) * 4 + csel];                                   \
    a47[SN][2] = A8n[(ar +  96) * 4 + csel];                                   \
    a47[SN][3] = A8n[(ar + 112) * 4 + csel];                                   \
    __builtin_amdgcn_sched_barrier(0);                                         \
    asm volatile("s_waitcnt lgkmcnt(4)" ::: "memory");                         \
    asm volatile("s_waitcnt vmcnt(4)" ::: "memory");                           \
    asm volatile("s_barrier" ::: "memory");                                    \
    __builtin_amdgcn_sched_barrier(0);                                         \
    __builtin_amdgcn_s_setprio(1);                                             \
    MF16(a03[SN], bv[SN], 0)                                                   \
    __builtin_amdgcn_s_setprio(0);                                             \
    __builtin_amdgcn_sched_barrier(0);                                         \
    if ((T) < TILES - 4) { pA0 += 32; pA1 += 32; pB0 += 32; pB1 += 32; }       \
  }

__global__ __launch_bounds__(512, 2) void gemm_bt(const ushort_t* __restrict__ A,
                                                  const ushort_t* __restrict__ B,
                                                  const float* __restrict__ bias,
                                                  float* __restrict__ C) {
  extern __shared__ ushort_t lds[];   // 4 bufs x 32KB = 128KB

  int bid = blockIdx.x;                     // 256 blocks
  int swz = (bid & 7) * 32 + (bid >> 3);    // bijective XCD swizzle
  int bm = swz >> 4;
  int bn = swz & 15;

  int tid  = threadIdx.x;
  int lane = tid & 63;
  int wave = tid >> 6;
  int wm = wave >> 2, wn = wave & 3;        // 2x4 wave grid: 128x64 per wave

  int l15  = lane & 15;
  int csel = (lane >> 4) ^ ((lane >> 1) & 3);

  int idx0 = tid, idx1 = 512 + tid;
  int sr0 = idx0 >> 2, scl0 = (idx0 & 3) ^ ((sr0 >> 1) & 3);
  int sr1 = idx1 >> 2, scl1 = (idx1 & 3) ^ ((sr1 >> 1) & 3);
  int ld0 = idx0 * 8, ld1 = idx1 * 8;
  const ushort_t* pA0 = A + (size_t)(bm * 256 + sr0) * D_IN + scl0 * 8;
  const ushort_t* pA1 = A + (size_t)(bm * 256 + sr1) * D_IN + scl1 * 8;
  const ushort_t* pB0 = B + (size_t)(bn * 256 + sr0) * D_IN + scl0 * 8;
  const ushort_t* pB1 = B + (size_t)(bn * 256 + sr1) * D_IN + scl1 * 8;

  f32x4 acc[8][4];
#pragma unroll
  for (int m = 0; m < 8; m++)
#pragma unroll
    for (int n = 0; n < 4; n++) acc[m][n] = (f32x4){0.f, 0.f, 0.f, 0.f};

  // prologue: stage tiles 0,1,2 (12 gloads)
  gload_lds16(pA0,      lds + ld0);         gload_lds16(pA1,      lds + ld1);
  gload_lds16(pB0,      lds + 8192 + ld0);  gload_lds16(pB1,      lds + 8192 + ld1);
  gload_lds16(pA0 + 32, lds + 16384 + ld0); gload_lds16(pA1 + 32, lds + 16384 + ld1);
  gload_lds16(pB0 + 32, lds + 24576 + ld0); gload_lds16(pB1 + 32, lds + 24576 + ld1);
  gload_lds16(pA0 + 64, lds + 32768 + ld0); gload_lds16(pA1 + 64, lds + 32768 + ld1);
  gload_lds16(pB0 + 64, lds + 40960 + ld0); gload_lds16(pB1 + 64, lds + 40960 + ld1);
  pA0 += 96; pA1 += 96; pB0 += 96; pB1 += 96;   // in-loop staging starts at tile 3
  asm volatile("s_waitcnt vmcnt(4)" ::: "memory");   // tiles 0,1 landed; tile 2 in flight
  asm volatile("s_barrier" ::: "memory");

  int ar = wm * 128 + l15;
  int br = wn * 64 + l15;

  bf16x8 bv[2][4], a03[2][4], a47[2][4];

  // prologue reads for tile 0 (set 0) + half1(0)
  {
    const bf16x8* A8 = (const bf16x8*)lds;
    const bf16x8* B8 = A8 + 1024;
    bv[0][0]  = B8[(br +  0) * 4 + csel];
    bv[0][1]  = B8[(br + 16) * 4 + csel];
    bv[0][2]  = B8[(br + 32) * 4 + csel];
    bv[0][3]  = B8[(br + 48) * 4 + csel];
    a03[0][0] = A8[(ar +  0) * 4 + csel];
    a03[0][1] = A8[(ar + 16) * 4 + csel];
    a03[0][2] = A8[(ar + 32) * 4 + csel];
    a03[0][3] = A8[(ar + 48) * 4 + csel];
    __builtin_amdgcn_sched_barrier(0);
    a47[0][0] = A8[(ar +  64) * 4 + csel];
    a47[0][1] = A8[(ar +  80) * 4 + csel];
    a47[0][2] = A8[(ar +  96) * 4 + csel];
    a47[0][3] = A8[(ar + 112) * 4 + csel];
    __builtin_amdgcn_sched_barrier(0);
    asm volatile("s_waitcnt lgkmcnt(4)" ::: "memory");
    __builtin_amdgcn_sched_barrier(0);
    __builtin_amdgcn_s_setprio(1);
    MF16(a03[0], bv[0], 0)
    __builtin_amdgcn_s_setprio(0);
    __builtin_amdgcn_sched_barrier(0);
  }

  // bodies 0..126 (each computes half2(T) + half1(T+1))
  for (int tt = 0; tt < 63; tt++) {
    int t0 = tt * 2;
    GBODY(t0, 0, 1)
    GBODY(t0 + 1, 1, 0)
  }
  GBODY(126, 0, 1)

  // tail: half2(127)
  asm volatile("s_waitcnt lgkmcnt(0)" ::: "memory");
  __builtin_amdgcn_sched_barrier(0);
  __builtin_amdgcn_s_setprio(1);
  MF16(a47[1], bv[1], 4)
  __builtin_amdgcn_s_setprio(0);

  int orow0 = bm * 256 + wm * 128 + (lane >> 4) * 4;
  int ocol0 = bn * 256 + wn * 64 + l15;
#pragma unroll
  for (int n = 0; n < 4; n++) {
    float bb = bias[ocol0 + n * 16];
#pragma unroll
    for (int m = 0; m < 8; m++) {
#pragma unroll
      for (int r = 0; r < 4; r++) {
        C[(size_t)(orow0 + m * 16 + r) * D_OUT + ocol0 + n * 16] = acc[m][n][r] + bb;
      }
    }
  }
}

// ---------- launch ----------
extern "C" void kernel_launch(void* const* d_in, const int* in_sizes, int n_in,
                              void* d_out, int out_size, void* d_ws, size_t ws_size,
                              hipStream_t stream) {
  const float* x = (const float*)d_in[0];
  const float* w = (const float*)d_in[1];
  const float* bias = (const float*)d_in[2];
  float* out = (float*)d_out;

  char* ws = (char*)d_ws;
  uint32* hist1 = (uint32*)ws;                       // 2048 bins @ 0
  uint32* hs1   = (uint32*)(ws + 8192);              // 1024 bins
  uint32* hs2   = (uint32*)(ws + 12288);             // 1024 bins
  uint32* cnt   = (uint32*)(ws + 16384);             // 1 word
  ushort_t* Xb  = (ushort_t*)(ws + 65536);
  ushort_t* Wb  = (ushort_t*)(ws + 65536 + (size_t)NW * 2);
  uint2*   cand = (uint2*)(ws + 65536 + (size_t)NW * 4);

  hipMemsetAsync(d_ws, 0, 16448, stream);

  k1_hist1_convx<<<3072, 256, 0, stream>>>((const uint4*)w, hist1, (const float4*)x, (uint4*)Xb);
  k2_decide<<<512, 256, 0, stream>>>((const float4*)w, hist1, (uint4*)Wb, cand, cnt);
  s1_hist<<<128, 256, 0, stream>>>(cand, cnt, hs1);
  s2_hist<<<128, 256, 0, stream>>>(cand, cnt, hist1, hs1, hs2);
  k5_fixup<<<256, 256, 0, stream>>>(cand, cnt, hist1, hs1, hs2, Wb);

  gemm_bt<<<256, 512, 131072, stream>>>(Xb, Wb, bias, out);
}